// Round 15
// baseline (186.876 us; speedup 1.0000x reference)
//
#include <hip/hip_runtime.h>
#include <hip/hip_cooperative_groups.h>

namespace cg = cooperative_groups;

// IoU assigner: N anchors x M gts (3D, 6 coords). Outputs (concatenated, f32):
//   out[0:N]   labels (-1 ignore, 0 neg, gt_label pos)
//   out[N:7N]  assigned boxes (gt box if pos, else -1.0)
//
// Bit-exact vs numpy f32: __f*_rn intrinsics (no FMA contraction), op order
// mirrors the jnp reference; argmax ties: first index.
//
// Round-15: SINGLE cooperative dispatch (was 3: memset+main+override, with
// ~20us of fixed dispatch/gap overhead measured constant across R9-R14).
//   phase1: R13's main body verbatim (grid-stride over 1954 logical blocks;
//           per-block gt maxima -> slotsPB rows, PLAIN stores: no zero-init,
//           so the memset dispatch dies too)
//   grid.sync()
//   phase2: blocks 0..127 reduce one gt column of slotsPB -> slotRed
//   grid.sync()
//   phase3: block 0 applies the low-quality override (proven logic)
// Spill-curse note: R3-R8's scratch demotion came from the ticket+early-
// return tail; R9-R14's barrier tails are clean. Phases here are uniform
// blockIdx-gated, no early return. Falsifiable: WRITE >> 16MB => spilled.
// Fallback to the proven 3-dispatch path if ws_size < slotsPB need.
//
// ws layout (coop): [0, nb*1024) slotsPB u64 rows; [nb*1024, +1024) slotRed.
// ws layout (fallback): [0,1024) slots u64.

#define MMAX 128

// One (gt, anchor-chain) IoU step on registers.
#define IOU_ONE(GLO, GHI, G, X0, Y0, Z0, X1, Y1, Z1, AR, BEST, ARG, ENC)       \
    {                                                                          \
        float cx = fmaxf(__fsub_rn(fminf(X1, GLO.w), fmaxf(X0, GLO.x)), 0.f);  \
        float cy = fmaxf(__fsub_rn(fminf(Y1, GHI.x), fmaxf(Y0, GLO.y)), 0.f);  \
        float cz = fmaxf(__fsub_rn(fminf(Z1, GHI.y), fmaxf(Z0, GLO.z)), 0.f);  \
        float inter = __fmul_rn(__fmul_rn(cx, cy), cz);                        \
        if (inter > 0.f) { /* ~0.3% of pairs */                                \
            float den = __fadd_rn(__fsub_rn(__fadd_rn(AR, GHI.z), inter), 1e-7f);\
            float iou = __fdiv_rn(inter, den);                                 \
            if (iou > BEST) { BEST = iou; ARG = (G); }                         \
            if (iou >= 0.3f) {                                                 \
                unsigned long long enc =                                       \
                    ((unsigned long long)__float_as_uint(iou) << 32) |         \
                    (unsigned long long)(ENC);                                 \
                atomicMax(&lsl[(G)], enc);                                     \
            }                                                                  \
        }                                                                      \
    }

#define IOU_G(GLO, GHI, G)                                                     \
    IOU_ONE(GLO, GHI, G, ax0, ay0, az0, ax1, ay1, az1, a1a, bestA, argA, encA) \
    IOU_ONE(GLO, GHI, G, bx0, by0, bz0, bx1, by1, bz1, a1b, bestB, argB, encB) \
    IOU_ONE(GLO, GHI, G, cx0, cy0, cz0, cx1, cy1, cz1, a1c, bestC, argC, encC) \
    IOU_ONE(GLO, GHI, G, dx0, dy0, dz0, dx1, dy1, dz1, a1d, bestD, argD, encD)

template <int MC>
__global__ __launch_bounds__(256) void iou_fused(
    const float* __restrict__ bx, const float* __restrict__ gt,
    const int* __restrict__ gl,
    float* __restrict__ out_lab, float* __restrict__ out_bb,
    unsigned long long* __restrict__ slotsPB,
    unsigned long long* __restrict__ slotRed,
    int N, int Mrt, int nb)
{
    const int M = MC ? MC : Mrt;
    const int tid  = threadIdx.x;
    const int lane = tid & 63;
    const int wv   = tid >> 6;

    __shared__ float4 gb4[MMAX * 2];  // [2g]={x0,y0,z0,x1} [2g+1]={y1,z1,area,label}
    __shared__ unsigned long long lsl[MMAX];   // per-gt column max (per logical block)
    __shared__ unsigned long long asl[256];    // per-anchor merge / phase2 reduce
    __shared__ int s_anchor[MMAX];
    __shared__ int s_cand[MMAX];

    // ---- stage gt tile once ----
    if (tid < M) {
        const float* gp = gt + (size_t)tid * 6;
        float x0 = gp[0], y0 = gp[1], z0 = gp[2];
        float x1 = gp[3], y1 = gp[4], z1 = gp[5];
        float area = __fmul_rn(__fmul_rn(__fsub_rn(x1, x0), __fsub_rn(y1, y0)),
                               __fsub_rn(z1, z0));
        gb4[2 * tid]     = make_float4(x0, y0, z0, x1);
        gb4[2 * tid + 1] = make_float4(y1, z1, area, (float)gl[tid]);
    }

    const int H = (N + 3) >> 2;
    const int chunk = (M + 3) >> 2;

    // ================= phase 1: grid-stride main =================
    for (int bid = blockIdx.x; (bid << 6) < H; bid += gridDim.x) {
        __syncthreads();                    // protect prev iteration's LDS readers
        if (tid < MMAX) lsl[tid] = 0ULL;
        asl[tid] = 0ULL;
        __syncthreads();

        const int base = bid * 64 + lane;
        const int a = base, b = base + H, c = base + 2 * H, d = base + 3 * H;
        const bool va = (base < H);
        const bool vb = va && (b < N);
        const bool vc = va && (c < N);
        const bool vd = va && (d < N);

        float ax0 = 0.f, ay0 = 0.f, az0 = 0.f, ax1 = 0.f, ay1 = 0.f, az1 = 0.f;
        if (va) { const float* p = bx + (size_t)a * 6;
            ax0 = p[0]; ay0 = p[1]; az0 = p[2]; ax1 = p[3]; ay1 = p[4]; az1 = p[5]; }
        float bx0 = 0.f, by0 = 0.f, bz0 = 0.f, bx1 = 0.f, by1 = 0.f, bz1 = 0.f;
        if (vb) { const float* p = bx + (size_t)b * 6;
            bx0 = p[0]; by0 = p[1]; bz0 = p[2]; bx1 = p[3]; by1 = p[4]; bz1 = p[5]; }
        float cx0 = 0.f, cy0 = 0.f, cz0 = 0.f, cx1 = 0.f, cy1 = 0.f, cz1 = 0.f;
        if (vc) { const float* p = bx + (size_t)c * 6;
            cx0 = p[0]; cy0 = p[1]; cz0 = p[2]; cx1 = p[3]; cy1 = p[4]; cz1 = p[5]; }
        float dx0 = 0.f, dy0 = 0.f, dz0 = 0.f, dx1 = 0.f, dy1 = 0.f, dz1 = 0.f;
        if (vd) { const float* p = bx + (size_t)d * 6;
            dx0 = p[0]; dy0 = p[1]; dz0 = p[2]; dx1 = p[3]; dy1 = p[4]; dz1 = p[5]; }

        const float a1a = __fmul_rn(__fmul_rn(__fsub_rn(ax1, ax0),
                           __fsub_rn(ay1, ay0)), __fsub_rn(az1, az0));
        const float a1b = __fmul_rn(__fmul_rn(__fsub_rn(bx1, bx0),
                           __fsub_rn(by1, by0)), __fsub_rn(bz1, bz0));
        const float a1c = __fmul_rn(__fmul_rn(__fsub_rn(cx1, cx0),
                           __fsub_rn(cy1, cy0)), __fsub_rn(cz1, cz0));
        const float a1d = __fmul_rn(__fmul_rn(__fsub_rn(dx1, dx0),
                           __fsub_rn(dy1, dy0)), __fsub_rn(dz1, dz0));

        const unsigned encA = 0xFFFFFFFFu - (unsigned)a;
        const unsigned encB = 0xFFFFFFFFu - (unsigned)b;
        const unsigned encC = 0xFFFFFFFFu - (unsigned)c;
        const unsigned encD = 0xFFFFFFFFu - (unsigned)d;

        const int g0 = wv * chunk;
        const int g1 = (g0 + chunk < M) ? (g0 + chunk) : M;

        float bestA = 0.f, bestB = 0.f, bestC = 0.f, bestD = 0.f;
        int   argA = g0,   argB = g0,   argC = g0,   argD = g0;

        int g = g0;
        for (; g + 3 < g1; g += 4) {
            const float4 glo0 = gb4[2*g+0], ghi0 = gb4[2*g+1];
            const float4 glo1 = gb4[2*g+2], ghi1 = gb4[2*g+3];
            const float4 glo2 = gb4[2*g+4], ghi2 = gb4[2*g+5];
            const float4 glo3 = gb4[2*g+6], ghi3 = gb4[2*g+7];
            IOU_G(glo0, ghi0, g + 0)
            IOU_G(glo1, ghi1, g + 1)
            IOU_G(glo2, ghi2, g + 2)
            IOU_G(glo3, ghi3, g + 3)
        }
        for (; g < g1; ++g) {               // tail (never taken at M=128)
            const float4 glo = gb4[2*g], ghi = gb4[2*g+1];
            IOU_G(glo, ghi, g)
        }

        if (va) atomicMax(&asl[0 * 64 + lane],
            ((unsigned long long)__float_as_uint(bestA) << 32) |
            (unsigned long long)(0xFFFFFFFFu - (unsigned)argA));
        if (vb) atomicMax(&asl[1 * 64 + lane],
            ((unsigned long long)__float_as_uint(bestB) << 32) |
            (unsigned long long)(0xFFFFFFFFu - (unsigned)argB));
        if (vc) atomicMax(&asl[2 * 64 + lane],
            ((unsigned long long)__float_as_uint(bestC) << 32) |
            (unsigned long long)(0xFFFFFFFFu - (unsigned)argC));
        if (vd) atomicMax(&asl[3 * 64 + lane],
            ((unsigned long long)__float_as_uint(bestD) << 32) |
            (unsigned long long)(0xFFFFFFFFu - (unsigned)argD));
        __syncthreads();

        // per-block gt maxima -> own row (plain store, no init required)
        if (tid < MMAX) slotsPB[(size_t)bid * MMAX + tid] = (tid < M) ? lsl[tid] : 0ULL;

        // epilogue: threads 0..255 own the 256 anchor slots
        {
            const int k = tid >> 6, l = tid & 63;
            const int sb = bid * 64 + l;
            const int anchor = sb + k * H;
            if (sb < H && anchor < N) {
                const unsigned long long v = asl[tid];
                const float best = __uint_as_float((unsigned)(v >> 32));
                const int garg = (int)(0xFFFFFFFFu - (unsigned)(v & 0xFFFFFFFFu));
                const float* gbf = (const float*)gb4;
                float lab;
                if (best >= 0.7f) lab = gbf[8 * garg + 7];
                else              lab = (best < 0.3f) ? 0.f : -1.f;
                out_lab[anchor] = lab;
                float* ob = out_bb + (size_t)anchor * 6;
                if (best >= 0.7f) {
                    ob[0] = gbf[8*garg+0]; ob[1] = gbf[8*garg+1]; ob[2] = gbf[8*garg+2];
                    ob[3] = gbf[8*garg+3]; ob[4] = gbf[8*garg+4]; ob[5] = gbf[8*garg+5];
                } else {
                    ob[0] = -1.f; ob[1] = -1.f; ob[2] = -1.f;
                    ob[3] = -1.f; ob[4] = -1.f; ob[5] = -1.f;
                }
            }
        }
    }

    cg::this_grid().sync();

    // ================= phase 2: per-gt column reduction =================
    if (blockIdx.x < MMAX) {
        const int g = blockIdx.x;
        unsigned long long best = 0ULL;
        for (int t = tid; t < nb; t += 256) {
            unsigned long long v = slotsPB[(size_t)t * MMAX + g];
            if (v > best) best = v;
        }
        asl[tid] = best;
        __syncthreads();
        for (int s = 128; s > 0; s >>= 1) {
            if (tid < s) {
                unsigned long long o = asl[tid + s];
                if (o > asl[tid]) asl[tid] = o;
            }
            __syncthreads();
        }
        if (tid == 0) slotRed[g] = asl[0];
    }

    cg::this_grid().sync();

    // ================= phase 3: low-quality override (block 0) =================
    if (blockIdx.x == 0) {
        int anchor = -1, cand = 0;
        if (tid < M) {
            unsigned long long v = slotRed[tid];
            if (v != 0ULL) {            // gt_iou_max >= 0.3 (gated at insert)
                anchor = (int)(0xFFFFFFFFu - (unsigned)(v & 0xFFFFFFFFu));
                cand   = tid + 1;
            }
        }
        if (tid < MMAX) { s_anchor[tid] = anchor; s_cand[tid] = cand; }
        __syncthreads();
        if (tid < M && cand > 0) {
            // Largest gt index targeting the same anchor wins (.at[].max scatter)
            bool win = true;
            for (int j = 0; j < M; ++j)
                if (s_cand[j] > cand && s_anchor[j] == anchor) win = false;
            if (win) {
                const float4 gl4 = gb4[2 * tid], gh4 = gb4[2 * tid + 1];
                out_lab[anchor] = gh4.w;
                float* ob = out_bb + (size_t)anchor * 6;
                ob[0] = gl4.x; ob[1] = gl4.y; ob[2] = gl4.z;
                ob[3] = gl4.w; ob[4] = gh4.x; ob[5] = gh4.y;
            }
        }
    }
}

// ---------------- fallback path (3 dispatches, proven R13) ----------------

template <int MC>
__global__ __launch_bounds__(256) void iou_main_legacy(
    const float* __restrict__ bx, const float* __restrict__ gt,
    const int* __restrict__ gl,
    float* __restrict__ out_lab, float* __restrict__ out_bb,
    unsigned long long* __restrict__ slots,
    int N, int Mrt)
{
    const int M = MC ? MC : Mrt;
    const int tid  = threadIdx.x;
    const int lane = tid & 63;
    const int wv   = tid >> 6;

    __shared__ float4 gb4[MMAX * 2];
    __shared__ unsigned long long lsl[MMAX];
    __shared__ unsigned long long asl[256];
    if (tid < M) {
        const float* gp = gt + (size_t)tid * 6;
        float x0 = gp[0], y0 = gp[1], z0 = gp[2];
        float x1 = gp[3], y1 = gp[4], z1 = gp[5];
        float area = __fmul_rn(__fmul_rn(__fsub_rn(x1, x0), __fsub_rn(y1, y0)),
                               __fsub_rn(z1, z0));
        gb4[2 * tid]     = make_float4(x0, y0, z0, x1);
        gb4[2 * tid + 1] = make_float4(y1, z1, area, (float)gl[tid]);
    }
    if (tid < MMAX) lsl[tid] = 0ULL;
    asl[tid] = 0ULL;
    __syncthreads();

    const int H = (N + 3) >> 2;
    const int base = blockIdx.x * 64 + lane;
    const int a = base, b = base + H, c = base + 2 * H, d = base + 3 * H;
    const bool va = (base < H);
    const bool vb = va && (b < N);
    const bool vc = va && (c < N);
    const bool vd = va && (d < N);

    float ax0 = 0.f, ay0 = 0.f, az0 = 0.f, ax1 = 0.f, ay1 = 0.f, az1 = 0.f;
    if (va) { const float* p = bx + (size_t)a * 6;
        ax0 = p[0]; ay0 = p[1]; az0 = p[2]; ax1 = p[3]; ay1 = p[4]; az1 = p[5]; }
    float bx0 = 0.f, by0 = 0.f, bz0 = 0.f, bx1 = 0.f, by1 = 0.f, bz1 = 0.f;
    if (vb) { const float* p = bx + (size_t)b * 6;
        bx0 = p[0]; by0 = p[1]; bz0 = p[2]; bx1 = p[3]; by1 = p[4]; bz1 = p[5]; }
    float cx0 = 0.f, cy0 = 0.f, cz0 = 0.f, cx1 = 0.f, cy1 = 0.f, cz1 = 0.f;
    if (vc) { const float* p = bx + (size_t)c * 6;
        cx0 = p[0]; cy0 = p[1]; cz0 = p[2]; cx1 = p[3]; cy1 = p[4]; cz1 = p[5]; }
    float dx0 = 0.f, dy0 = 0.f, dz0 = 0.f, dx1 = 0.f, dy1 = 0.f, dz1 = 0.f;
    if (vd) { const float* p = bx + (size_t)d * 6;
        dx0 = p[0]; dy0 = p[1]; dz0 = p[2]; dx1 = p[3]; dy1 = p[4]; dz1 = p[5]; }

    const float a1a = __fmul_rn(__fmul_rn(__fsub_rn(ax1, ax0),
                       __fsub_rn(ay1, ay0)), __fsub_rn(az1, az0));
    const float a1b = __fmul_rn(__fmul_rn(__fsub_rn(bx1, bx0),
                       __fsub_rn(by1, by0)), __fsub_rn(bz1, bz0));
    const float a1c = __fmul_rn(__fmul_rn(__fsub_rn(cx1, cx0),
                       __fsub_rn(cy1, cy0)), __fsub_rn(cz1, cz0));
    const float a1d = __fmul_rn(__fmul_rn(__fsub_rn(dx1, dx0),
                       __fsub_rn(dy1, dy0)), __fsub_rn(dz1, dz0));

    const unsigned encA = 0xFFFFFFFFu - (unsigned)a;
    const unsigned encB = 0xFFFFFFFFu - (unsigned)b;
    const unsigned encC = 0xFFFFFFFFu - (unsigned)c;
    const unsigned encD = 0xFFFFFFFFu - (unsigned)d;

    const int chunk = (M + 3) >> 2;
    const int g0 = wv * chunk;
    const int g1 = (g0 + chunk < M) ? (g0 + chunk) : M;

    float bestA = 0.f, bestB = 0.f, bestC = 0.f, bestD = 0.f;
    int   argA = g0,   argB = g0,   argC = g0,   argD = g0;

    int g = g0;
    for (; g + 3 < g1; g += 4) {
        const float4 glo0 = gb4[2*g+0], ghi0 = gb4[2*g+1];
        const float4 glo1 = gb4[2*g+2], ghi1 = gb4[2*g+3];
        const float4 glo2 = gb4[2*g+4], ghi2 = gb4[2*g+5];
        const float4 glo3 = gb4[2*g+6], ghi3 = gb4[2*g+7];
        IOU_G(glo0, ghi0, g + 0)
        IOU_G(glo1, ghi1, g + 1)
        IOU_G(glo2, ghi2, g + 2)
        IOU_G(glo3, ghi3, g + 3)
    }
    for (; g < g1; ++g) {
        const float4 glo = gb4[2*g], ghi = gb4[2*g+1];
        IOU_G(glo, ghi, g)
    }

    if (va) atomicMax(&asl[0 * 64 + lane],
        ((unsigned long long)__float_as_uint(bestA) << 32) |
        (unsigned long long)(0xFFFFFFFFu - (unsigned)argA));
    if (vb) atomicMax(&asl[1 * 64 + lane],
        ((unsigned long long)__float_as_uint(bestB) << 32) |
        (unsigned long long)(0xFFFFFFFFu - (unsigned)argB));
    if (vc) atomicMax(&asl[2 * 64 + lane],
        ((unsigned long long)__float_as_uint(bestC) << 32) |
        (unsigned long long)(0xFFFFFFFFu - (unsigned)argC));
    if (vd) atomicMax(&asl[3 * 64 + lane],
        ((unsigned long long)__float_as_uint(bestD) << 32) |
        (unsigned long long)(0xFFFFFFFFu - (unsigned)argD));
    __syncthreads();

    if (tid < M) {
        unsigned long long v = lsl[tid];
        if (v) atomicMax(&slots[tid], v);
    }

    {
        const int k = tid >> 6, l = tid & 63;
        const int sb = blockIdx.x * 64 + l;
        const int anchor = sb + k * H;
        if (sb < H && anchor < N) {
            const unsigned long long v = asl[tid];
            const float best = __uint_as_float((unsigned)(v >> 32));
            const int garg = (int)(0xFFFFFFFFu - (unsigned)(v & 0xFFFFFFFFu));
            const float* gbf = (const float*)gb4;
            float lab;
            if (best >= 0.7f) lab = gbf[8 * garg + 7];
            else              lab = (best < 0.3f) ? 0.f : -1.f;
            out_lab[anchor] = lab;
            float* ob = out_bb + (size_t)anchor * 6;
            if (best >= 0.7f) {
                ob[0] = gbf[8*garg+0]; ob[1] = gbf[8*garg+1]; ob[2] = gbf[8*garg+2];
                ob[3] = gbf[8*garg+3]; ob[4] = gbf[8*garg+4]; ob[5] = gbf[8*garg+5];
            } else {
                ob[0] = -1.f; ob[1] = -1.f; ob[2] = -1.f;
                ob[3] = -1.f; ob[4] = -1.f; ob[5] = -1.f;
            }
        }
    }
}

__global__ __launch_bounds__(MMAX) void iou_override_legacy(
    const float* __restrict__ gt, const int* __restrict__ gl,
    const unsigned long long* __restrict__ slots,
    float* __restrict__ out_lab, float* __restrict__ out_bb, int M)
{
    __shared__ int s_anchor[MMAX];
    __shared__ int s_cand[MMAX];
    const int i = threadIdx.x;

    int anchor = -1, cand = 0;
    if (i < M) {
        unsigned long long v = slots[i];
        if (v != 0ULL) {
            anchor = (int)(0xFFFFFFFFu - (unsigned)(v & 0xFFFFFFFFu));
            cand   = i + 1;
        }
    }
    s_anchor[i] = anchor;
    s_cand[i]   = cand;
    __syncthreads();

    if (cand > 0) {
        bool win = true;
        for (int j = 0; j < M; ++j)
            if (s_cand[j] > cand && s_anchor[j] == anchor) { win = false; break; }
        if (win) {
            out_lab[anchor] = (float)gl[i];
            float* ob = out_bb + (size_t)anchor * 6;
            const float* gp = gt + (size_t)i * 6;
            ob[0] = gp[0]; ob[1] = gp[1]; ob[2] = gp[2];
            ob[3] = gp[3]; ob[4] = gp[4]; ob[5] = gp[5];
        }
    }
}

extern "C" void kernel_launch(void* const* d_in, const int* in_sizes, int n_in,
                              void* d_out, int out_size, void* d_ws, size_t ws_size,
                              hipStream_t stream)
{
    const float* bx = (const float*)d_in[0];
    const float* gt = (const float*)d_in[1];
    const int*   gl = (const int*)d_in[2];
    const int N = in_sizes[0] / 6;
    int M = in_sizes[1] / 6;
    if (M > MMAX) M = MMAX;

    float* out_lab = (float*)d_out;
    float* out_bb  = (float*)d_out + N;

    const int H = (N + 3) / 4;
    const int nb = (H + 63) / 64;                 // logical blocks
    const size_t needPB = (size_t)nb * MMAX * 8 + MMAX * 8;

    if (ws_size >= needPB) {
        // -------- single cooperative dispatch --------
        unsigned long long* slotsPB = (unsigned long long*)d_ws;
        unsigned long long* slotRed =
            (unsigned long long*)((char*)d_ws + (size_t)nb * MMAX * 8);

        int bpc = 0;
        if (M == MMAX) {
            hipOccupancyMaxActiveBlocksPerMultiprocessor(
                &bpc, (const void*)iou_fused<MMAX>, 256, 0);
        } else {
            hipOccupancyMaxActiveBlocksPerMultiprocessor(
                &bpc, (const void*)iou_fused<0>, 256, 0);
        }
        if (bpc < 1) bpc = 1;
        int dev = 0, ncu = 256;
        hipGetDevice(&dev);
        hipDeviceGetAttribute(&ncu, hipDeviceAttributeMultiprocessorCount, dev);
        int grid = bpc * ncu;
        if (grid > nb) grid = nb;
        if (grid < MMAX) grid = MMAX;             // need 128 blocks for phase 2

        void* args[] = { (void*)&bx, (void*)&gt, (void*)&gl,
                         (void*)&out_lab, (void*)&out_bb,
                         (void*)&slotsPB, (void*)&slotRed,
                         (void*)&N, (void*)&M, (void*)&nb };
        if (M == MMAX) {
            hipLaunchCooperativeKernel((const void*)iou_fused<MMAX>,
                                       dim3(grid), dim3(256), args, 0, stream);
        } else {
            hipLaunchCooperativeKernel((const void*)iou_fused<0>,
                                       dim3(grid), dim3(256), args, 0, stream);
        }
    } else {
        // -------- proven 3-dispatch fallback (R13) --------
        unsigned long long* slots = (unsigned long long*)d_ws;
        hipMemsetAsync(d_ws, 0, MMAX * 8, stream);
        if (M == MMAX) {
            hipLaunchKernelGGL(iou_main_legacy<MMAX>, dim3(nb), dim3(256), 0, stream,
                               bx, gt, gl, out_lab, out_bb, slots, N, M);
        } else {
            hipLaunchKernelGGL(iou_main_legacy<0>, dim3(nb), dim3(256), 0, stream,
                               bx, gt, gl, out_lab, out_bb, slots, N, M);
        }
        hipLaunchKernelGGL(iou_override_legacy, dim3(1), dim3(MMAX), 0, stream,
                           gt, gl, slots, out_lab, out_bb, M);
    }
}

// Round 16
// 64.061 us; speedup vs baseline: 2.9172x; 2.9172x over previous
//
#include <hip/hip_runtime.h>

// IoU assigner: N anchors x M gts (3D, 6 coords). Outputs (concatenated, f32):
//   out[0:N]   labels (-1 ignore, 0 neg, gt_label pos)
//   out[N:7N]  assigned boxes (gt box if pos, else -1.0)
//
// Bit-exact vs numpy f32: __f*_rn intrinsics (no FMA contraction), op order
// mirrors the jnp reference; argmax ties: first index (strict > scan; the
// cross-chunk merge encodes (iou_bits<<32)|~g so max picks smallest g).
//
// Round-16: R13 skeleton (3 dispatches, proven clean; R15's cooperative
// fusion spilled: WRITE 25.9MB, 273us) + ONE change: gt operands delivered
// via UNIFORM (readfirstlane) loads -> SMEM s_load into SGPRs, consumed
// directly by VALU. Each wave handles its 32-gt chunk as 4 sub-chunks of
// 8 gts: preload 48 uniform floats, one drain, then 32 IoU instances of
// pure memory-free VALU. Removes the steady-state ds_read->lgkmcnt round
// trip that R12-R14 kept hitting (43-47us wall at ~30% issue).
// UNFUSED override + explicit memset (fusing provably spills: R3-R8, R15).
//
// ws layout: [0,1024) slots[128] u64.

#define MMAX 128

// ---- generic-path macros (R13 verbatim): gt operands from LDS float4 ----
#define IOU_ONE(GLO, GHI, G, X0, Y0, Z0, X1, Y1, Z1, AR, BEST, ARG, ENC)       \
    {                                                                          \
        float cx = fmaxf(__fsub_rn(fminf(X1, GLO.w), fmaxf(X0, GLO.x)), 0.f);  \
        float cy = fmaxf(__fsub_rn(fminf(Y1, GHI.x), fmaxf(Y0, GLO.y)), 0.f);  \
        float cz = fmaxf(__fsub_rn(fminf(Z1, GHI.y), fmaxf(Z0, GLO.z)), 0.f);  \
        float inter = __fmul_rn(__fmul_rn(cx, cy), cz);                        \
        if (inter > 0.f) {                                                     \
            float den = __fadd_rn(__fsub_rn(__fadd_rn(AR, GHI.z), inter), 1e-7f);\
            float iou = __fdiv_rn(inter, den);                                 \
            if (iou > BEST) { BEST = iou; ARG = (G); }                         \
            if (iou >= 0.3f) {                                                 \
                unsigned long long enc =                                       \
                    ((unsigned long long)__float_as_uint(iou) << 32) |         \
                    (unsigned long long)(ENC);                                 \
                atomicMax(&lsl[(G)], enc);                                     \
            }                                                                  \
        }                                                                      \
    }

#define IOU_G(GLO, GHI, G)                                                     \
    IOU_ONE(GLO, GHI, G, ax0, ay0, az0, ax1, ay1, az1, a1a, bestA, argA, encA) \
    IOU_ONE(GLO, GHI, G, bx0, by0, bz0, bx1, by1, bz1, a1b, bestB, argB, encB) \
    IOU_ONE(GLO, GHI, G, cx0, cy0, cz0, cx1, cy1, cz1, a1c, bestC, argC, encC) \
    IOU_ONE(GLO, GHI, G, dx0, dy0, dz0, dx1, dy1, dz1, a1d, bestD, argD, encD)

// ---- fast-path macros: gt operands from uniform (scalar) loads ----
#define LOAD_GT(J)                                                             \
    const float q##J##x0 = gq[(J)*6+0], q##J##y0 = gq[(J)*6+1],                \
                q##J##z0 = gq[(J)*6+2], q##J##x1 = gq[(J)*6+3],                \
                q##J##y1 = gq[(J)*6+4], q##J##z1 = gq[(J)*6+5];                \
    const float q##J##ar = __fmul_rn(__fmul_rn(__fsub_rn(q##J##x1, q##J##x0),  \
                            __fsub_rn(q##J##y1, q##J##y0)),                    \
                            __fsub_rn(q##J##z1, q##J##z0));

#define IOU_S(J, X0, Y0, Z0, X1, Y1, Z1, AR, BEST, ARG, ENC)                   \
    {                                                                          \
        float cx = fmaxf(__fsub_rn(fminf(X1, q##J##x1), fmaxf(X0, q##J##x0)), 0.f);\
        float cy = fmaxf(__fsub_rn(fminf(Y1, q##J##y1), fmaxf(Y0, q##J##y0)), 0.f);\
        float cz = fmaxf(__fsub_rn(fminf(Z1, q##J##z1), fmaxf(Z0, q##J##z0)), 0.f);\
        float inter = __fmul_rn(__fmul_rn(cx, cy), cz);                        \
        if (inter > 0.f) { /* ~0.3% of pairs */                                \
            float den = __fadd_rn(__fsub_rn(__fadd_rn(AR, q##J##ar), inter), 1e-7f);\
            float iou = __fdiv_rn(inter, den);                                 \
            if (iou > BEST) { BEST = iou; ARG = u + (J); }                     \
            if (iou >= 0.3f) {                                                 \
                unsigned long long enc =                                       \
                    ((unsigned long long)__float_as_uint(iou) << 32) |         \
                    (unsigned long long)(ENC);                                 \
                atomicMax(&lsl[u + (J)], enc);                                 \
            }                                                                  \
        }                                                                      \
    }

#define IOU_GT4(J)                                                             \
    IOU_S(J, ax0, ay0, az0, ax1, ay1, az1, a1a, bestA, argA, encA)             \
    IOU_S(J, bx0, by0, bz0, bx1, by1, bz1, a1b, bestB, argB, encB)             \
    IOU_S(J, cx0, cy0, cz0, cx1, cy1, cz1, a1c, bestC, argC, encC)             \
    IOU_S(J, dx0, dy0, dz0, dx1, dy1, dz1, a1d, bestD, argD, encD)

template <int MC>
__global__ __launch_bounds__(256) void iou_main(
    const float* __restrict__ bx, const float* __restrict__ gt,
    const int* __restrict__ gl,
    float* __restrict__ out_lab, float* __restrict__ out_bb,
    unsigned long long* __restrict__ slots,
    int N, int Mrt)
{
    const int M = MC ? MC : Mrt;
    const int tid  = threadIdx.x;
    const int lane = tid & 63;
    const int wv   = tid >> 6;

    // ---- stage gt tile (epilogue/generic use); zero LDS slots ----
    __shared__ float4 gb4[MMAX * 2];  // [2g]={x0,y0,z0,x1} [2g+1]={y1,z1,area,label}
    __shared__ unsigned long long lsl[MMAX];   // per-gt column max
    __shared__ unsigned long long asl[256];    // per-anchor (best,arg) merge
    if (tid < M) {
        const float* gp = gt + (size_t)tid * 6;
        float x0 = gp[0], y0 = gp[1], z0 = gp[2];
        float x1 = gp[3], y1 = gp[4], z1 = gp[5];
        float area = __fmul_rn(__fmul_rn(__fsub_rn(x1, x0), __fsub_rn(y1, y0)),
                               __fsub_rn(z1, z0));
        gb4[2 * tid]     = make_float4(x0, y0, z0, x1);
        gb4[2 * tid + 1] = make_float4(y1, z1, area, (float)gl[tid]);
    }
    if (tid < MMAX) lsl[tid] = 0ULL;
    asl[tid] = 0ULL;
    __syncthreads();

    // ---- four anchors per LANE at stride H; all 4 waves share them ----
    const int H = (N + 3) >> 2;
    const int base = blockIdx.x * 64 + lane;
    const int a = base, b = base + H, c = base + 2 * H, d = base + 3 * H;
    const bool va = (base < H);
    const bool vb = va && (b < N);
    const bool vc = va && (c < N);
    const bool vd = va && (d < N);

    float ax0 = 0.f, ay0 = 0.f, az0 = 0.f, ax1 = 0.f, ay1 = 0.f, az1 = 0.f;
    if (va) { const float* p = bx + (size_t)a * 6;
        ax0 = p[0]; ay0 = p[1]; az0 = p[2]; ax1 = p[3]; ay1 = p[4]; az1 = p[5]; }
    float bx0 = 0.f, by0 = 0.f, bz0 = 0.f, bx1 = 0.f, by1 = 0.f, bz1 = 0.f;
    if (vb) { const float* p = bx + (size_t)b * 6;
        bx0 = p[0]; by0 = p[1]; bz0 = p[2]; bx1 = p[3]; by1 = p[4]; bz1 = p[5]; }
    float cx0 = 0.f, cy0 = 0.f, cz0 = 0.f, cx1 = 0.f, cy1 = 0.f, cz1 = 0.f;
    if (vc) { const float* p = bx + (size_t)c * 6;
        cx0 = p[0]; cy0 = p[1]; cz0 = p[2]; cx1 = p[3]; cy1 = p[4]; cz1 = p[5]; }
    float dx0 = 0.f, dy0 = 0.f, dz0 = 0.f, dx1 = 0.f, dy1 = 0.f, dz1 = 0.f;
    if (vd) { const float* p = bx + (size_t)d * 6;
        dx0 = p[0]; dy0 = p[1]; dz0 = p[2]; dx1 = p[3]; dy1 = p[4]; dz1 = p[5]; }

    const float a1a = __fmul_rn(__fmul_rn(__fsub_rn(ax1, ax0),
                       __fsub_rn(ay1, ay0)), __fsub_rn(az1, az0));
    const float a1b = __fmul_rn(__fmul_rn(__fsub_rn(bx1, bx0),
                       __fsub_rn(by1, by0)), __fsub_rn(bz1, bz0));
    const float a1c = __fmul_rn(__fmul_rn(__fsub_rn(cx1, cx0),
                       __fsub_rn(cy1, cy0)), __fsub_rn(cz1, cz0));
    const float a1d = __fmul_rn(__fmul_rn(__fsub_rn(dx1, dx0),
                       __fsub_rn(dy1, dy0)), __fsub_rn(dz1, dz0));

    const unsigned encA = 0xFFFFFFFFu - (unsigned)a;   // loop-invariant
    const unsigned encB = 0xFFFFFFFFu - (unsigned)b;
    const unsigned encC = 0xFFFFFFFFu - (unsigned)c;
    const unsigned encD = 0xFFFFFFFFu - (unsigned)d;

    const int chunk = (M + 3) >> 2;
    const int g0w = wv * chunk;

    float bestA = 0.f, bestB = 0.f, bestC = 0.f, bestD = 0.f;
    int   argA = g0w,  argB = g0w,  argC = g0w,  argD = g0w;

    if constexpr (MC == MMAX) {
        // ---- fast path: 4 sub-chunks of 8 gts; 48 uniform floats preloaded
        //      via readfirstlane-uniform address (-> SMEM s_load), then 32
        //      memory-free IoU instances per sub-chunk ----
        for (int cs = 0; cs < 32; cs += 8) {
            const int u = __builtin_amdgcn_readfirstlane(g0w + cs);
            const float* gq = gt + (size_t)u * 6;
            LOAD_GT(0) LOAD_GT(1) LOAD_GT(2) LOAD_GT(3)
            LOAD_GT(4) LOAD_GT(5) LOAD_GT(6) LOAD_GT(7)
            IOU_GT4(0) IOU_GT4(1) IOU_GT4(2) IOU_GT4(3)
            IOU_GT4(4) IOU_GT4(5) IOU_GT4(6) IOU_GT4(7)
        }
    } else {
        // ---- generic path (runtime M): R13 LDS loop ----
        const int g1 = (g0w + chunk < M) ? (g0w + chunk) : M;
        int g = g0w;
        for (; g + 3 < g1; g += 4) {
            const float4 glo0 = gb4[2*g+0], ghi0 = gb4[2*g+1];
            const float4 glo1 = gb4[2*g+2], ghi1 = gb4[2*g+3];
            const float4 glo2 = gb4[2*g+4], ghi2 = gb4[2*g+5];
            const float4 glo3 = gb4[2*g+6], ghi3 = gb4[2*g+7];
            IOU_G(glo0, ghi0, g + 0)
            IOU_G(glo1, ghi1, g + 1)
            IOU_G(glo2, ghi2, g + 2)
            IOU_G(glo3, ghi3, g + 3)
        }
        for (; g < g1; ++g) {
            const float4 glo = gb4[2*g], ghi = gb4[2*g+1];
            IOU_G(glo, ghi, g)
        }
    }

    // ---- merge per-anchor chunk results: (iou_bits<<32)|~g, max = best iou,
    //      smallest g on ties (first-index argmax across the full 0..M-1) ----
    if (va) atomicMax(&asl[0 * 64 + lane],
        ((unsigned long long)__float_as_uint(bestA) << 32) |
        (unsigned long long)(0xFFFFFFFFu - (unsigned)argA));
    if (vb) atomicMax(&asl[1 * 64 + lane],
        ((unsigned long long)__float_as_uint(bestB) << 32) |
        (unsigned long long)(0xFFFFFFFFu - (unsigned)argB));
    if (vc) atomicMax(&asl[2 * 64 + lane],
        ((unsigned long long)__float_as_uint(bestC) << 32) |
        (unsigned long long)(0xFFFFFFFFu - (unsigned)argC));
    if (vd) atomicMax(&asl[3 * 64 + lane],
        ((unsigned long long)__float_as_uint(bestD) << 32) |
        (unsigned long long)(0xFFFFFFFFu - (unsigned)argD));
    __syncthreads();

    // ---- flush per-gt maxima to global slots ----
    if (tid < M) {
        unsigned long long v = lsl[tid];
        if (v) atomicMax(&slots[tid], v);
    }

    // ---- epilogue: threads own the 256 anchor slots ----
    {
        const int k = tid >> 6, l = tid & 63;
        const int sb = blockIdx.x * 64 + l;
        const int anchor = sb + k * H;
        if (sb < H && anchor < N) {
            const unsigned long long v = asl[tid];
            const float best = __uint_as_float((unsigned)(v >> 32));
            const int garg = (int)(0xFFFFFFFFu - (unsigned)(v & 0xFFFFFFFFu));
            const float* gbf = (const float*)gb4;   // [8g+0..5]=box +6=area +7=label
            float lab;
            if (best >= 0.7f) lab = gbf[8 * garg + 7];
            else              lab = (best < 0.3f) ? 0.f : -1.f;
            out_lab[anchor] = lab;
            float* ob = out_bb + (size_t)anchor * 6;
            if (best >= 0.7f) {
                ob[0] = gbf[8*garg+0]; ob[1] = gbf[8*garg+1]; ob[2] = gbf[8*garg+2];
                ob[3] = gbf[8*garg+3]; ob[4] = gbf[8*garg+4]; ob[5] = gbf[8*garg+5];
            } else {
                ob[0] = -1.f; ob[1] = -1.f; ob[2] = -1.f;
                ob[3] = -1.f; ob[4] = -1.f; ob[5] = -1.f;
            }
        }
    }
}

// Low-quality override (separate dispatch — fusing this tail provably makes
// hipcc spill the main loop's live set: R3-R8 ticket, R15 cooperative): for
// each gt with a nonzero slot (column max >= 0.3), its argmax anchor gets
// that gt; when several gts pick the same anchor the LARGEST gt index wins
// (mirrors the reference's .at[].max scatter).
__global__ __launch_bounds__(MMAX) void iou_override(
    const float* __restrict__ gt, const int* __restrict__ gl,
    const unsigned long long* __restrict__ slots,
    float* __restrict__ out_lab, float* __restrict__ out_bb, int M)
{
    __shared__ int s_anchor[MMAX];
    __shared__ int s_cand[MMAX];
    const int i = threadIdx.x;

    int anchor = -1, cand = 0;
    if (i < M) {
        unsigned long long v = slots[i];
        if (v != 0ULL) {               // gt_iou_max >= 0.3 (gated at insert)
            anchor = (int)(0xFFFFFFFFu - (unsigned)(v & 0xFFFFFFFFu));
            cand   = i + 1;
        }
    }
    s_anchor[i] = anchor;
    s_cand[i]   = cand;
    __syncthreads();

    if (cand > 0) {
        bool win = true;
        for (int j = 0; j < M; ++j)
            if (s_cand[j] > cand && s_anchor[j] == anchor) { win = false; break; }
        if (win) {
            out_lab[anchor] = (float)gl[i];
            float* ob = out_bb + (size_t)anchor * 6;
            const float* gp = gt + (size_t)i * 6;
            ob[0] = gp[0]; ob[1] = gp[1]; ob[2] = gp[2];
            ob[3] = gp[3]; ob[4] = gp[4]; ob[5] = gp[5];
        }
    }
}

extern "C" void kernel_launch(void* const* d_in, const int* in_sizes, int n_in,
                              void* d_out, int out_size, void* d_ws, size_t ws_size,
                              hipStream_t stream)
{
    const float* bx = (const float*)d_in[0];
    const float* gt = (const float*)d_in[1];
    const int*   gl = (const int*)d_in[2];
    const int N = in_sizes[0] / 6;
    int M = in_sizes[1] / 6;
    if (M > MMAX) M = MMAX;

    float* out_lab = (float*)d_out;
    float* out_bb  = (float*)d_out + N;

    unsigned long long* slots = (unsigned long long*)d_ws;

    // slots MUST be re-zeroed every call (ws is poisoned once, not re-poisoned
    // between timed replays; first post-poison replay sees 0xAA ws).
    hipMemsetAsync(d_ws, 0, MMAX * 8, stream);

    const int H = (N + 3) / 4;
    const int nblocks = (H + 63) / 64;

    if (M == MMAX) {
        hipLaunchKernelGGL(iou_main<MMAX>, dim3(nblocks), dim3(256), 0, stream,
                           bx, gt, gl, out_lab, out_bb, slots, N, M);
    } else {
        hipLaunchKernelGGL(iou_main<0>, dim3(nblocks), dim3(256), 0, stream,
                           bx, gt, gl, out_lab, out_bb, slots, N, M);
    }
    hipLaunchKernelGGL(iou_override, dim3(1), dim3(MMAX), 0, stream,
                       gt, gl, slots, out_lab, out_bb, M);
}